// Round 1
// baseline (643.386 us; speedup 1.0000x reference)
//
#include <hip/hip_runtime.h>

// CostVolume v4 — 4 output pixels (consecutive x) per thread, fp32 in/out.
// out[n,d,y,x] = (1/64) * sum_c in1_pad[n,c, y+dy_d-4, x+dx_d-4] * in2[n,c,y,x]
// N=8 C=64 H=160 W=320; 53 (dy,dx) offsets of a 9x9 window (MD=4).
//
// Key change vs v3 (81 guarded scalar loads/channel): one thread owns x0..x0+3,
// so each window row is 12 floats = 3 aligned float4 loads shared by all 4
// pixels and all dx offsets -> 28 vector loads/channel instead of 81 scalar.
// NO guards in the inner loop: row index is clamped to [0,159] and the two
// boundary loads are clamped to the buffer; any garbage so produced lands only
// in acc[d][px] slots whose TRUE source index (y+dy-4, x0+px+dx-4) is out of
// bounds -- those are zeroed in the epilogue (matches reference zero-padding,
// since OOB-ness of a given (d,pixel) is uniform across channels).
//
// acc[53] as float4 => ~240 VGPR, 2 waves/SIMD (__launch_bounds__(64,2)).
// 64-thread blocks, 1600 blocks; bijective XCD swizzle (bid&7)*200+(bid>>3)
// gives each XCD exactly one image n (L2 working set ~740KB << 4MB/XCD).

#define HH 160
#define WW 320
#define CHN 64
#define ND 53
#define HW4 (HH * WW * 4)      /* 204800 bytes per (n,c) plane */
#define ROW4 (WW * 4)          /* 1280 bytes per row */
#define IMG4 (CHN * HW4)       /* 13107200 bytes per n image */
#define SIZEB (8 * IMG4)       /* 104857600 bytes total in1 */
#define OIMG4 (ND * HW4)       /* out bytes per n */

__global__ __launch_bounds__(64, 2)
void cost_volume_x4(const float* __restrict__ in1,
                    const float* __restrict__ in2,
                    float* __restrict__ out) {
    // XCD-aware swizzle: default round-robin bid->XCD becomes contiguous
    // 200-block chunks; 200 blocks == exactly one n image.
    const int bid = blockIdx.x;
    const int sb  = (bid & 7) * 200 + (bid >> 3);
    const int g   = sb * 64 + threadIdx.x;

    const int xg = g % 80;            // x-group: 4 pixels
    const int x0 = xg * 4;
    const int y  = (g / 80) % HH;
    const int n  = g / (80 * HH);

    const char* p1 = (const char*)in1;
    const char* p2 = (const char*)in2;

    float4 acc[ND];
    #pragma unroll
    for (int d = 0; d < ND; ++d) acc[d] = make_float4(0.f, 0.f, 0.f, 0.f);

    int pc = n * IMG4 + x0 * 4 - 16;              // in1 byte base (c=0,row 0,x0-4)
    int i2 = n * IMG4 + (y * WW + x0) * 4;        // in2 byte offset (c=0)

    #pragma unroll 1
    for (int c = 0; c < CHN; ++c) {
        const float4 w = *(const float4*)(p2 + i2);
        float f[12];   // window row: x0-4 .. x0+7 (all compile-time indexed)

        // Row DY: clamp row to [0,159]; clamp first/last load vs buffer ends.
        // Mid load (off+16) is always in [0, SIZEB-16] since off >= -16.
        #define ROWLOAD(DY) { \
            int yy = y + (DY) - 4; \
            yy = yy < 0 ? 0 : (yy > HH - 1 ? HH - 1 : yy); \
            const int off = pc + yy * ROW4; \
            const int o0 = off < 0 ? 0 : off; \
            const int o2 = (off + 32 > SIZEB - 16) ? (SIZEB - 16) : (off + 32); \
            const float4 a  = *(const float4*)(p1 + o0); \
            const float4 b  = *(const float4*)(p1 + off + 16); \
            const float4 cc = *(const float4*)(p1 + o2); \
            f[0] = a.x;  f[1] = a.y;  f[2]  = a.z;  f[3]  = a.w; \
            f[4] = b.x;  f[5] = b.y;  f[6]  = b.z;  f[7]  = b.w; \
            f[8] = cc.x; f[9] = cc.y; f[10] = cc.z; f[11] = cc.w; }

        // acc[D] pixel px accumulates f[DX+px] * w[px]  (x index = x0+px+DX-4)
        #define ACC(D, DX) \
            acc[D].x = fmaf(f[(DX) + 0], w.x, acc[D].x); \
            acc[D].y = fmaf(f[(DX) + 1], w.y, acc[D].y); \
            acc[D].z = fmaf(f[(DX) + 2], w.z, acc[D].z); \
            acc[D].w = fmaf(f[(DX) + 3], w.w, acc[D].w);

        ROWLOAD(0) ACC(0,0)  ACC(1,2)  ACC(2,4)  ACC(3,6)  ACC(4,8)
        ROWLOAD(1) ACC(5,1)  ACC(6,3)  ACC(7,5)  ACC(8,7)
        ROWLOAD(2) ACC(9,0)  ACC(10,2) ACC(11,3) ACC(12,4) ACC(13,5) ACC(14,6) ACC(15,8)
        ROWLOAD(3) ACC(16,1) ACC(17,2) ACC(18,3) ACC(19,4) ACC(20,5) ACC(21,6) ACC(22,7)
        ROWLOAD(4) ACC(23,0) ACC(24,2) ACC(25,3) ACC(26,4) ACC(27,5) ACC(28,6) ACC(29,8)
        ROWLOAD(5) ACC(30,1) ACC(31,2) ACC(32,3) ACC(33,4) ACC(34,5) ACC(35,6) ACC(36,7)
        ROWLOAD(6) ACC(37,0) ACC(38,2) ACC(39,3) ACC(40,4) ACC(41,5) ACC(42,6) ACC(43,8)
        ROWLOAD(7) ACC(44,1) ACC(45,3) ACC(46,5) ACC(47,7)
        ROWLOAD(8) ACC(48,0) ACC(49,2) ACC(50,4) ACC(51,6) ACC(52,8)
        #undef ROWLOAD
        #undef ACC

        pc += HW4;
        i2 += HW4;
    }

    // Epilogue: apply zero-padding mask once (valid iff true source in-bounds),
    // scale by 1/64, vector store.
    const float s = 1.0f / 64.0f;
    char* po = (char*)out + (size_t)n * OIMG4 + (size_t)((y * WW + x0) * 4);

    bool xok[12];
    #pragma unroll
    for (int j = 0; j < 12; ++j) {
        const int xx = x0 + j - 4;
        xok[j] = (xx >= 0) && (xx < WW);
    }

    #define EPI(D, DY, DX) { \
        const int yy = y + (DY) - 4; \
        const bool ry = (yy >= 0) && (yy < HH); \
        float4 r; \
        r.x = (ry && xok[(DX) + 0]) ? acc[D].x * s : 0.f; \
        r.y = (ry && xok[(DX) + 1]) ? acc[D].y * s : 0.f; \
        r.z = (ry && xok[(DX) + 2]) ? acc[D].z * s : 0.f; \
        r.w = (ry && xok[(DX) + 3]) ? acc[D].w * s : 0.f; \
        *(float4*)(po + (D) * HW4) = r; }

    EPI(0,0,0)  EPI(1,0,2)  EPI(2,0,4)  EPI(3,0,6)  EPI(4,0,8)
    EPI(5,1,1)  EPI(6,1,3)  EPI(7,1,5)  EPI(8,1,7)
    EPI(9,2,0)  EPI(10,2,2) EPI(11,2,3) EPI(12,2,4) EPI(13,2,5) EPI(14,2,6) EPI(15,2,8)
    EPI(16,3,1) EPI(17,3,2) EPI(18,3,3) EPI(19,3,4) EPI(20,3,5) EPI(21,3,6) EPI(22,3,7)
    EPI(23,4,0) EPI(24,4,2) EPI(25,4,3) EPI(26,4,4) EPI(27,4,5) EPI(28,4,6) EPI(29,4,8)
    EPI(30,5,1) EPI(31,5,2) EPI(32,5,3) EPI(33,5,4) EPI(34,5,5) EPI(35,5,6) EPI(36,5,7)
    EPI(37,6,0) EPI(38,6,2) EPI(39,6,3) EPI(40,6,4) EPI(41,6,5) EPI(42,6,6) EPI(43,6,8)
    EPI(44,7,1) EPI(45,7,3) EPI(46,7,5) EPI(47,7,7)
    EPI(48,8,0) EPI(49,8,2) EPI(50,8,4) EPI(51,8,6) EPI(52,8,8)
    #undef EPI
}

extern "C" void kernel_launch(void* const* d_in, const int* in_sizes, int n_in,
                              void* d_out, int out_size, void* d_ws, size_t ws_size,
                              hipStream_t stream) {
    const float* in1 = (const float*)d_in[0];
    const float* in2 = (const float*)d_in[1];
    float* out = (float*)d_out;

    // 8*160*80 = 102400 threads, one per (n, y, x-group-of-4)
    dim3 grid(1600);
    dim3 block(64);
    cost_volume_x4<<<grid, block, 0, stream>>>(in1, in2, out);
}

// Round 2
// 641.871 us; speedup vs baseline: 1.0024x; 1.0024x over previous
//
#include <hip/hip_runtime.h>

// CostVolume v5 — same x4 structure as v4, but occupancy PINNED to 2 waves/EU.
//
// v4 post-mortem: __launch_bounds__(64,2) only sets a MINIMUM waves/EU; LLVM's
// heuristic targeted the 128-VGPR / 4-wave tier and spilled ~6 accumulators to
// scratch per channel iteration (WRITE_SIZE 84.8 -> 247.6 MB, VALUBusy 27 -> 8%,
// dur 306 -> 497us). Fix: amdgpu_waves_per_eu(2,2) pins min=max=2 -> 256-VGPR
// budget. Accumulator layout needs ~240 regs (53 x float4 acc + 12 f + 4 w +
// addressing), which fits with zero spill.
//
// Structure recap:
//   out[n,d,y,x] = (1/64) * sum_c in1_pad[n,c, y+dy_d-4, x+dx_d-4] * in2[n,c,y,x]
//   One thread owns 4 consecutive x pixels. Per channel: one 12-float window
//   row = 3 aligned float4 loads shared by all 4 pixels and all dx offsets
//   (4 VMEM + 212 FMA per channel vs v3's 81 guarded scalar loads).
//   No guards in the inner loop: row index clamped to [0,159], boundary loads
//   clamped into the buffer; garbage lands only in acc slots whose TRUE source
//   index is out of bounds, zeroed once in the epilogue (OOB-ness of a given
//   (d,pixel) is uniform across channels -> matches reference zero-padding).
//   XCD swizzle (bid&7)*200+(bid>>3): 200 blocks == exactly one n image.

#define HH 160
#define WW 320
#define CHN 64
#define ND 53
#define HW4 (HH * WW * 4)      /* 204800 bytes per (n,c) plane */
#define ROW4 (WW * 4)          /* 1280 bytes per row */
#define IMG4 (CHN * HW4)       /* 13107200 bytes per n image */
#define SIZEB (8 * IMG4)       /* 104857600 bytes total in1 */
#define OIMG4 (ND * HW4)       /* out bytes per n */

__global__
__attribute__((amdgpu_flat_work_group_size(64, 64), amdgpu_waves_per_eu(2, 2)))
void cost_volume_x4(const float* __restrict__ in1,
                    const float* __restrict__ in2,
                    float* __restrict__ out) {
    const int bid = blockIdx.x;
    const int sb  = (bid & 7) * 200 + (bid >> 3);
    const int g   = sb * 64 + threadIdx.x;

    const int xg = g % 80;            // x-group: 4 pixels
    const int x0 = xg * 4;
    const int y  = (g / 80) % HH;
    const int n  = g / (80 * HH);

    const char* p1 = (const char*)in1;
    const char* p2 = (const char*)in2;

    float4 acc[ND];
    #pragma unroll
    for (int d = 0; d < ND; ++d) acc[d] = make_float4(0.f, 0.f, 0.f, 0.f);

    int pc = n * IMG4 + x0 * 4 - 16;              // in1 byte base (c=0,row 0,x0-4)
    int i2 = n * IMG4 + (y * WW + x0) * 4;        // in2 byte offset (c=0)

    #pragma unroll 1
    for (int c = 0; c < CHN; ++c) {
        const float4 w = *(const float4*)(p2 + i2);
        float f[12];   // window row: x0-4 .. x0+7 (all compile-time indexed)

        // Row DY: clamp row to [0,159]; clamp first/last load vs buffer ends.
        // Mid load (off+16) is always in [0, SIZEB-16] since off >= -16.
        #define ROWLOAD(DY) { \
            int yy = y + (DY) - 4; \
            yy = yy < 0 ? 0 : (yy > HH - 1 ? HH - 1 : yy); \
            const int off = pc + yy * ROW4; \
            const int o0 = off < 0 ? 0 : off; \
            const int o2 = (off + 32 > SIZEB - 16) ? (SIZEB - 16) : (off + 32); \
            const float4 a  = *(const float4*)(p1 + o0); \
            const float4 b  = *(const float4*)(p1 + off + 16); \
            const float4 cc = *(const float4*)(p1 + o2); \
            f[0] = a.x;  f[1] = a.y;  f[2]  = a.z;  f[3]  = a.w; \
            f[4] = b.x;  f[5] = b.y;  f[6]  = b.z;  f[7]  = b.w; \
            f[8] = cc.x; f[9] = cc.y; f[10] = cc.z; f[11] = cc.w; }

        // acc[D] pixel px accumulates f[DX+px] * w[px]  (x index = x0+px+DX-4)
        #define ACC(D, DX) \
            acc[D].x = fmaf(f[(DX) + 0], w.x, acc[D].x); \
            acc[D].y = fmaf(f[(DX) + 1], w.y, acc[D].y); \
            acc[D].z = fmaf(f[(DX) + 2], w.z, acc[D].z); \
            acc[D].w = fmaf(f[(DX) + 3], w.w, acc[D].w);

        ROWLOAD(0) ACC(0,0)  ACC(1,2)  ACC(2,4)  ACC(3,6)  ACC(4,8)
        ROWLOAD(1) ACC(5,1)  ACC(6,3)  ACC(7,5)  ACC(8,7)
        ROWLOAD(2) ACC(9,0)  ACC(10,2) ACC(11,3) ACC(12,4) ACC(13,5) ACC(14,6) ACC(15,8)
        ROWLOAD(3) ACC(16,1) ACC(17,2) ACC(18,3) ACC(19,4) ACC(20,5) ACC(21,6) ACC(22,7)
        ROWLOAD(4) ACC(23,0) ACC(24,2) ACC(25,3) ACC(26,4) ACC(27,5) ACC(28,6) ACC(29,8)
        ROWLOAD(5) ACC(30,1) ACC(31,2) ACC(32,3) ACC(33,4) ACC(34,5) ACC(35,6) ACC(36,7)
        ROWLOAD(6) ACC(37,0) ACC(38,2) ACC(39,3) ACC(40,4) ACC(41,5) ACC(42,6) ACC(43,8)
        ROWLOAD(7) ACC(44,1) ACC(45,3) ACC(46,5) ACC(47,7)
        ROWLOAD(8) ACC(48,0) ACC(49,2) ACC(50,4) ACC(51,6) ACC(52,8)
        #undef ROWLOAD
        #undef ACC

        pc += HW4;
        i2 += HW4;
    }

    // Epilogue: apply zero-padding mask once (valid iff true source in-bounds),
    // scale by 1/64, vector store.
    const float s = 1.0f / 64.0f;
    char* po = (char*)out + (size_t)n * OIMG4 + (size_t)((y * WW + x0) * 4);

    bool xok[12];
    #pragma unroll
    for (int j = 0; j < 12; ++j) {
        const int xx = x0 + j - 4;
        xok[j] = (xx >= 0) && (xx < WW);
    }

    #define EPI(D, DY, DX) { \
        const int yy = y + (DY) - 4; \
        const bool ry = (yy >= 0) && (yy < HH); \
        float4 r; \
        r.x = (ry && xok[(DX) + 0]) ? acc[D].x * s : 0.f; \
        r.y = (ry && xok[(DX) + 1]) ? acc[D].y * s : 0.f; \
        r.z = (ry && xok[(DX) + 2]) ? acc[D].z * s : 0.f; \
        r.w = (ry && xok[(DX) + 3]) ? acc[D].w * s : 0.f; \
        *(float4*)(po + (D) * HW4) = r; }

    EPI(0,0,0)  EPI(1,0,2)  EPI(2,0,4)  EPI(3,0,6)  EPI(4,0,8)
    EPI(5,1,1)  EPI(6,1,3)  EPI(7,1,5)  EPI(8,1,7)
    EPI(9,2,0)  EPI(10,2,2) EPI(11,2,3) EPI(12,2,4) EPI(13,2,5) EPI(14,2,6) EPI(15,2,8)
    EPI(16,3,1) EPI(17,3,2) EPI(18,3,3) EPI(19,3,4) EPI(20,3,5) EPI(21,3,6) EPI(22,3,7)
    EPI(23,4,0) EPI(24,4,2) EPI(25,4,3) EPI(26,4,4) EPI(27,4,5) EPI(28,4,6) EPI(29,4,8)
    EPI(30,5,1) EPI(31,5,2) EPI(32,5,3) EPI(33,5,4) EPI(34,5,5) EPI(35,5,6) EPI(36,5,7)
    EPI(37,6,0) EPI(38,6,2) EPI(39,6,3) EPI(40,6,4) EPI(41,6,5) EPI(42,6,6) EPI(43,6,8)
    EPI(44,7,1) EPI(45,7,3) EPI(46,7,5) EPI(47,7,7)
    EPI(48,8,0) EPI(49,8,2) EPI(50,8,4) EPI(51,8,6) EPI(52,8,8)
    #undef EPI
}

extern "C" void kernel_launch(void* const* d_in, const int* in_sizes, int n_in,
                              void* d_out, int out_size, void* d_ws, size_t ws_size,
                              hipStream_t stream) {
    const float* in1 = (const float*)d_in[0];
    const float* in2 = (const float*)d_in[1];
    float* out = (float*)d_out;

    // 8*160*80 = 102400 threads, one per (n, y, x-group-of-4)
    dim3 grid(1600);
    dim3 block(64);
    cost_volume_x4<<<grid, block, 0, stream>>>(in1, in2, out);
}

// Round 3
// 419.657 us; speedup vs baseline: 1.5331x; 1.5295x over previous
//
#include <hip/hip_runtime.h>

// CostVolume v6 — x4 pixels/thread, 53 offsets SPLIT into 3 dy-groups across
// 3x the blocks. Fixes v4/v5's two structural defects:
//  1) Register demand: v4/v5 needed ~240 VGPRs but the allocator granted 128
//     regardless of launch_bounds/waves_per_eu attributes -> ~25B/thread/chan
//     scratch round-trip on the dependency chain (WRITE_SIZE 85->249MB).
//     Now the worst pass holds 21 float4 accs (~115 VGPRs incl. window+addr)
//     -> fits the 128 budget with zero spill by construction.
//  2) Latency hiding: 1600 waves (1.56/SIMD, Occupancy 18%) couldn't hide
//     anything. Now 4800 blocks = 4.7 waves/SIMD.
// dy-groups partition the 9 window rows exactly -> in1 rows are NOT re-read
// across passes; only in2 is read 3x (L3-resident, in1+in2=210MB < 256MB L3).
//
// out[n,d,y,x] = (1/64) * sum_c in1_pad[n,c, y+dy_d-4, x+dx_d-4] * in2[n,c,y,x]
// One thread owns 4 consecutive x. Window row = 12 floats = 3 aligned float4
// loads shared by 4 pixels and all dx. No guards in the inner loop: row index
// clamped to [0,159], boundary loads clamped into the buffer; garbage lands
// only in acc slots whose TRUE source index is OOB, zeroed in the epilogue
// (OOB-ness of a (d,pixel) is uniform across channels == reference zero-pad).
// XCD swizzle (bid&7)*600+(bid>>3): contiguous pass/image chunk per XCD.

#define HH 160
#define WW 320
#define CHN 64
#define ND 53
#define HW4 (HH * WW * 4)      /* 204800 bytes per (n,c) plane */
#define ROW4 (WW * 4)          /* 1280 bytes per row */
#define IMG4 (CHN * HW4)       /* 13107200 bytes per n image */
#define SIZEB (8 * IMG4)       /* 104857600 bytes total in1 */
#define OIMG4 (ND * HW4)       /* out bytes per n */

__global__ __launch_bounds__(64, 4)
void cost_volume_split(const float* __restrict__ in1,
                       const float* __restrict__ in2,
                       float* __restrict__ out) {
    const int bid = blockIdx.x;                  // 0..4799
    const int u   = (bid & 7) * 600 + (bid >> 3); // contiguous chunk per XCD
    const int p   = u / 1600;                    // dy-group: rows 3p..3p+2
    const int r   = u % 1600;
    const int g   = r * 64 + threadIdx.x;        // 0..102399

    const int xg = g % 80;
    const int x0 = xg * 4;
    const int y  = (g / 80) % HH;
    const int n  = g / (80 * HH);

    const char* p1 = (const char*)in1;
    const char* p2 = (const char*)in2;

    int pc = n * IMG4 + x0 * 4 - 16;             // in1 byte base (c=0,row0,x0-4)
    int i2 = n * IMG4 + (y * WW + x0) * 4;       // in2 byte offset (c=0)

    const float s = 1.0f / 64.0f;
    char* po = (char*)out + (size_t)n * OIMG4 + (size_t)((y * WW + x0) * 4);

    bool xok[12];
    #pragma unroll
    for (int j = 0; j < 12; ++j) {
        const int xx = x0 + j - 4;
        xok[j] = (xx >= 0) && (xx < WW);
    }

    // Row DY: clamp row to [0,159]; clamp first/last load vs buffer ends.
    // Mid load (off+16) is always in [0, SIZEB-16] since off >= -16.
    #define ROWLOAD(DY) { \
        int yy = y + (DY) - 4; \
        yy = yy < 0 ? 0 : (yy > HH - 1 ? HH - 1 : yy); \
        const int off = pc + yy * ROW4; \
        const int o0 = off < 0 ? 0 : off; \
        const int o2 = (off + 32 > SIZEB - 16) ? (SIZEB - 16) : (off + 32); \
        const float4 a  = *(const float4*)(p1 + o0); \
        const float4 b  = *(const float4*)(p1 + off + 16); \
        const float4 cc = *(const float4*)(p1 + o2); \
        f[0] = a.x;  f[1] = a.y;  f[2]  = a.z;  f[3]  = a.w; \
        f[4] = b.x;  f[5] = b.y;  f[6]  = b.z;  f[7]  = b.w; \
        f[8] = cc.x; f[9] = cc.y; f[10] = cc.z; f[11] = cc.w; }

    #define ACC4(A, DX) \
        acc[A].x = fmaf(f[(DX) + 0], w.x, acc[A].x); \
        acc[A].y = fmaf(f[(DX) + 1], w.y, acc[A].y); \
        acc[A].z = fmaf(f[(DX) + 2], w.z, acc[A].z); \
        acc[A].w = fmaf(f[(DX) + 3], w.w, acc[A].w);

    #define EPI(A, D, DY, DX) { \
        const int yy = y + (DY) - 4; \
        const bool ry = (yy >= 0) && (yy < HH); \
        float4 rr; \
        rr.x = (ry && xok[(DX) + 0]) ? acc[A].x * s : 0.f; \
        rr.y = (ry && xok[(DX) + 1]) ? acc[A].y * s : 0.f; \
        rr.z = (ry && xok[(DX) + 2]) ? acc[A].z * s : 0.f; \
        rr.w = (ry && xok[(DX) + 3]) ? acc[A].w * s : 0.f; \
        *(float4*)(po + (D) * HW4) = rr; }

    if (p == 0) {
        // dy 0,1,2 -> d 0..15
        float4 acc[16];
        #pragma unroll
        for (int a = 0; a < 16; ++a) acc[a] = make_float4(0.f, 0.f, 0.f, 0.f);
        #pragma unroll 1
        for (int c = 0; c < CHN; ++c) {
            const float4 w = *(const float4*)(p2 + i2);
            float f[12];
            ROWLOAD(0) ACC4(0,0)  ACC4(1,2)  ACC4(2,4)  ACC4(3,6)  ACC4(4,8)
            ROWLOAD(1) ACC4(5,1)  ACC4(6,3)  ACC4(7,5)  ACC4(8,7)
            ROWLOAD(2) ACC4(9,0)  ACC4(10,2) ACC4(11,3) ACC4(12,4) ACC4(13,5) ACC4(14,6) ACC4(15,8)
            pc += HW4; i2 += HW4;
        }
        EPI(0,0,0,0)   EPI(1,1,0,2)   EPI(2,2,0,4)   EPI(3,3,0,6)   EPI(4,4,0,8)
        EPI(5,5,1,1)   EPI(6,6,1,3)   EPI(7,7,1,5)   EPI(8,8,1,7)
        EPI(9,9,2,0)   EPI(10,10,2,2) EPI(11,11,2,3) EPI(12,12,2,4)
        EPI(13,13,2,5) EPI(14,14,2,6) EPI(15,15,2,8)
    } else if (p == 1) {
        // dy 3,4,5 -> d 16..36
        float4 acc[21];
        #pragma unroll
        for (int a = 0; a < 21; ++a) acc[a] = make_float4(0.f, 0.f, 0.f, 0.f);
        #pragma unroll 1
        for (int c = 0; c < CHN; ++c) {
            const float4 w = *(const float4*)(p2 + i2);
            float f[12];
            ROWLOAD(3) ACC4(0,1)  ACC4(1,2)  ACC4(2,3)  ACC4(3,4)  ACC4(4,5)  ACC4(5,6)  ACC4(6,7)
            ROWLOAD(4) ACC4(7,0)  ACC4(8,2)  ACC4(9,3)  ACC4(10,4) ACC4(11,5) ACC4(12,6) ACC4(13,8)
            ROWLOAD(5) ACC4(14,1) ACC4(15,2) ACC4(16,3) ACC4(17,4) ACC4(18,5) ACC4(19,6) ACC4(20,7)
            pc += HW4; i2 += HW4;
        }
        EPI(0,16,3,1)  EPI(1,17,3,2)  EPI(2,18,3,3)  EPI(3,19,3,4)
        EPI(4,20,3,5)  EPI(5,21,3,6)  EPI(6,22,3,7)
        EPI(7,23,4,0)  EPI(8,24,4,2)  EPI(9,25,4,3)  EPI(10,26,4,4)
        EPI(11,27,4,5) EPI(12,28,4,6) EPI(13,29,4,8)
        EPI(14,30,5,1) EPI(15,31,5,2) EPI(16,32,5,3) EPI(17,33,5,4)
        EPI(18,34,5,5) EPI(19,35,5,6) EPI(20,36,5,7)
    } else {
        // dy 6,7,8 -> d 37..52
        float4 acc[16];
        #pragma unroll
        for (int a = 0; a < 16; ++a) acc[a] = make_float4(0.f, 0.f, 0.f, 0.f);
        #pragma unroll 1
        for (int c = 0; c < CHN; ++c) {
            const float4 w = *(const float4*)(p2 + i2);
            float f[12];
            ROWLOAD(6) ACC4(0,0)  ACC4(1,2)  ACC4(2,3)  ACC4(3,4)  ACC4(4,5)  ACC4(5,6)  ACC4(6,8)
            ROWLOAD(7) ACC4(7,1)  ACC4(8,3)  ACC4(9,5)  ACC4(10,7)
            ROWLOAD(8) ACC4(11,0) ACC4(12,2) ACC4(13,4) ACC4(14,6) ACC4(15,8)
            pc += HW4; i2 += HW4;
        }
        EPI(0,37,6,0)  EPI(1,38,6,2)  EPI(2,39,6,3)  EPI(3,40,6,4)
        EPI(4,41,6,5)  EPI(5,42,6,6)  EPI(6,43,6,8)
        EPI(7,44,7,1)  EPI(8,45,7,3)  EPI(9,46,7,5)  EPI(10,47,7,7)
        EPI(11,48,8,0) EPI(12,49,8,2) EPI(13,50,8,4) EPI(14,51,8,6) EPI(15,52,8,8)
    }
    #undef ROWLOAD
    #undef ACC4
    #undef EPI
}

extern "C" void kernel_launch(void* const* d_in, const int* in_sizes, int n_in,
                              void* d_out, int out_size, void* d_ws, size_t ws_size,
                              hipStream_t stream) {
    const float* in1 = (const float*)d_in[0];
    const float* in2 = (const float*)d_in[1];
    float* out = (float*)d_out;

    // 3 dy-groups x 8*160*80/64 blocks = 4800 blocks of 64 threads
    dim3 grid(4800);
    dim3 block(64);
    cost_volume_split<<<grid, block, 0, stream>>>(in1, in2, out);
}

// Round 5
// 376.891 us; speedup vs baseline: 1.7071x; 1.1135x over previous
//
#include <hip/hip_runtime.h>

// CostVolume v7 — 5 dy-passes, double-buffered channel pipeline, 128-reg tier.
// (Resubmission of Round-3 source: the Round-4 bench died to a container/infra
// failure with no counters; OOB + pipeline + graph-capture audits found no
// kernel-side cause. Theory and predictions unchanged.)
//
// v6 post-mortem: __launch_bounds__(64,4) made the allocator squeeze to 64
// arch-VGPRs (demand ~100-136) -> loads issued in waitcnt-separated batches,
// ~2700 cyc/channel-iter of serialized memory latency (VALUBusy 13.8%, HBM 19%,
// Occupancy 26% -- latency-bound, nothing saturated). Fix:
//  1) 5 passes {dy0-1,dy2-3,dy4-5,dy6-7,dy8}: max 14 float4 accs (56 regs) +
//     2-row double-buffered stage (2x28) ~= 120 regs -> fits the 128-reg tier
//     that __launch_bounds__(64,2) empirically grants (v4 evidence).
//  2) Hand-unrolled x2 channel loop: stage c+1's 7 loads issue BEFORE c's FMAs
//     -> latency overlapped instead of serialized.
//  3) 8000 waves (7.8/SIMD of work) vs v6's 4800; resident cap 4/SIMD @128reg.
// in2 is demanded 5x but in1+in2 = 210MB < 256MB L3 -> HBM fetch rises mildly.
//
// out[n,d,y,x] = (1/64) * sum_c in1_pad[n,c, y+dy_d-4, x+dx_d-4] * in2[n,c,y,x]
// One thread owns 4 consecutive x. Window row = 12 floats = 3 aligned float4
// loads shared by 4 pixels and all dx. No guards in the hot loop: row index
// clamped to [0,159], first/last loads clamped into the buffer; garbage lands
// only in acc slots whose TRUE source index is OOB, zeroed in the epilogue
// (OOB-ness of a (d,pixel) is uniform across channels == reference zero-pad).

#define HH 160
#define WW 320
#define CHN 64
#define ND 53
#define HW4 (HH * WW * 4)      /* 204800 bytes per (n,c) plane */
#define ROW4 (WW * 4)          /* 1280 bytes per row */
#define IMG4 (CHN * HW4)       /* 13107200 bytes per n image */
#define SIZEB (8 * IMG4)       /* 104857600 bytes total in1 */
#define OIMG4 (ND * HW4)       /* out bytes per n */

__global__ __launch_bounds__(64, 2)
void cost_volume_5p(const float* __restrict__ in1,
                    const float* __restrict__ in2,
                    float* __restrict__ out) {
    const int bid = blockIdx.x;                   // 0..7999
    const int u   = (bid & 7) * 1000 + (bid >> 3); // bijective XCD swizzle
    const int p   = u / 1600;                     // pass 0..4
    const int r   = u % 1600;
    const int g   = r * 64 + threadIdx.x;

    const int xg = g % 80;
    const int x0 = xg * 4;
    const int y  = (g / 80) % HH;
    const int n  = g / (80 * HH);

    const char* p1 = (const char*)in1;
    const char* p2 = (const char*)in2;

    int pc = n * IMG4 + x0 * 4 - 16;              // in1 byte base (c0,row0,x0-4)
    int i2 = n * IMG4 + (y * WW + x0) * 4;        // in2 byte offset (c0)

    // clamped in-plane byte offset of window row dy
    #define RYOFF(DY) \
        (((y + (DY) - 4) < 0 ? 0 : ((y + (DY) - 4) > HH - 1 ? HH - 1 : (y + (DY) - 4))) * ROW4)

    // Load one 12-float window row (3 float4, ends clamped into buffer) at
    // plane offset PC + RO into FS[J0..J0+11].
    #define LDROW(FS, J0, PC, RO) { \
        const int off = (PC) + (RO); \
        const int oa = off < 0 ? 0 : off; \
        const int oc = (off + 32 > SIZEB - 16) ? (SIZEB - 16) : (off + 32); \
        const float4 va = *(const float4*)(p1 + oa); \
        const float4 vb = *(const float4*)(p1 + off + 16); \
        const float4 vc = *(const float4*)(p1 + oc); \
        FS[(J0)+0] = va.x; FS[(J0)+1]  = va.y; FS[(J0)+2]  = va.z; FS[(J0)+3]  = va.w; \
        FS[(J0)+4] = vb.x; FS[(J0)+5]  = vb.y; FS[(J0)+6]  = vb.z; FS[(J0)+7]  = vb.w; \
        FS[(J0)+8] = vc.x; FS[(J0)+9]  = vc.y; FS[(J0)+10] = vc.z; FS[(J0)+11] = vc.w; }

    #define LOAD2(FS, WS, PC, I2) { \
        WS = *(const float4*)(p2 + (I2)); \
        LDROW(FS, 0, PC, r0) \
        LDROW(FS, 12, PC, r1) }

    #define LOAD1(FS, WS, PC, I2) { \
        WS = *(const float4*)(p2 + (I2)); \
        LDROW(FS, 0, PC, r0) }

    // acc[A] pixel px += FS[J+px] * WS[px]   (J = row_base + dx)
    #define AC(A, J, FS, WS) \
        acc[A].x = fmaf(FS[(J)+0], WS.x, acc[A].x); \
        acc[A].y = fmaf(FS[(J)+1], WS.y, acc[A].y); \
        acc[A].z = fmaf(FS[(J)+2], WS.z, acc[A].z); \
        acc[A].w = fmaf(FS[(J)+3], WS.w, acc[A].w);

    // Double-buffered channel loop: stage c+1 issues before c's FMAs.
    #define CHANLOOP(LOADM, CMPM) \
        LOADM(fA, wA, pc, i2) \
        _Pragma("unroll 1") \
        for (int c = 0; c < CHN - 2; c += 2) { \
            LOADM(fB, wB, pc + HW4, i2 + HW4) \
            CMPM(fA, wA) \
            pc += 2 * HW4; i2 += 2 * HW4; \
            LOADM(fA, wA, pc, i2) \
            CMPM(fB, wB) \
        } \
        LOADM(fB, wB, pc + HW4, i2 + HW4) \
        CMPM(fA, wA) \
        CMPM(fB, wB)

    #define EPI(A, D, RY, DX) { \
        float4 rr; \
        rr.x = ((RY) && xok[(DX)+0]) ? acc[A].x * s : 0.f; \
        rr.y = ((RY) && xok[(DX)+1]) ? acc[A].y * s : 0.f; \
        rr.z = ((RY) && xok[(DX)+2]) ? acc[A].z * s : 0.f; \
        rr.w = ((RY) && xok[(DX)+3]) ? acc[A].w * s : 0.f; \
        *(float4*)(po + (size_t)(D) * HW4) = rr; }

    #define EPIPRE \
        const float s = 1.0f / 64.0f; \
        char* po = (char*)out + (size_t)n * OIMG4 + (size_t)((y * WW + x0) * 4); \
        bool xok[12]; \
        _Pragma("unroll") \
        for (int j = 0; j < 12; ++j) { const int xx = x0 + j - 4; xok[j] = (xx >= 0) && (xx < WW); }

    if (p == 0) {
        // dy0 -> d0..4 dx{0,2,4,6,8}; dy1 -> d5..8 dx{1,3,5,7}
        const int r0 = RYOFF(0), r1 = RYOFF(1);
        float4 acc[9];
        #pragma unroll
        for (int a = 0; a < 9; ++a) acc[a] = make_float4(0.f,0.f,0.f,0.f);
        float fA[24], fB[24]; float4 wA, wB;
        #define CMP0(FS, WS) \
            AC(0,0,FS,WS)  AC(1,2,FS,WS)  AC(2,4,FS,WS)  AC(3,6,FS,WS)  AC(4,8,FS,WS) \
            AC(5,13,FS,WS) AC(6,15,FS,WS) AC(7,17,FS,WS) AC(8,19,FS,WS)
        CHANLOOP(LOAD2, CMP0)
        EPIPRE
        const bool ry0 = (y >= 4);            // y+0-4 in [0,160)
        const bool ry1 = (y >= 3);
        EPI(0,0,ry0,0) EPI(1,1,ry0,2) EPI(2,2,ry0,4) EPI(3,3,ry0,6) EPI(4,4,ry0,8)
        EPI(5,5,ry1,1) EPI(6,6,ry1,3) EPI(7,7,ry1,5) EPI(8,8,ry1,7)
    } else if (p <= 2) {
        // p=1: dy2 -> d9..15 dx{0,2,3,4,5,6,8}; dy3 -> d16..22 dx{1..7}
        // p=2: dy4 -> d23..29 same dx; dy5 -> d30..36 same dx
        const int dyA = 2 * p;                 // 2 or 4
        const int r0 = RYOFF(dyA), r1 = RYOFF(dyA + 1);
        const int dbase = 9 + (p - 1) * 14;
        float4 acc[14];
        #pragma unroll
        for (int a = 0; a < 14; ++a) acc[a] = make_float4(0.f,0.f,0.f,0.f);
        float fA[24], fB[24]; float4 wA, wB;
        #define CMP12(FS, WS) \
            AC(0,0,FS,WS)   AC(1,2,FS,WS)   AC(2,3,FS,WS)   AC(3,4,FS,WS) \
            AC(4,5,FS,WS)   AC(5,6,FS,WS)   AC(6,8,FS,WS) \
            AC(7,13,FS,WS)  AC(8,14,FS,WS)  AC(9,15,FS,WS)  AC(10,16,FS,WS) \
            AC(11,17,FS,WS) AC(12,18,FS,WS) AC(13,19,FS,WS)
        CHANLOOP(LOAD2, CMP12)
        EPIPRE
        const int ya = y + dyA - 4, yb = ya + 1;
        const bool ryA = (ya >= 0) && (ya < HH);
        const bool ryB = (yb >= 0) && (yb < HH);
        EPI(0,dbase+0,ryA,0)  EPI(1,dbase+1,ryA,2)  EPI(2,dbase+2,ryA,3)
        EPI(3,dbase+3,ryA,4)  EPI(4,dbase+4,ryA,5)  EPI(5,dbase+5,ryA,6)
        EPI(6,dbase+6,ryA,8)
        EPI(7,dbase+7,ryB,1)  EPI(8,dbase+8,ryB,2)  EPI(9,dbase+9,ryB,3)
        EPI(10,dbase+10,ryB,4) EPI(11,dbase+11,ryB,5) EPI(12,dbase+12,ryB,6)
        EPI(13,dbase+13,ryB,7)
    } else if (p == 3) {
        // dy6 -> d37..43 dx{0,2,3,4,5,6,8}; dy7 -> d44..47 dx{1,3,5,7}
        const int r0 = RYOFF(6), r1 = RYOFF(7);
        float4 acc[11];
        #pragma unroll
        for (int a = 0; a < 11; ++a) acc[a] = make_float4(0.f,0.f,0.f,0.f);
        float fA[24], fB[24]; float4 wA, wB;
        #define CMP3(FS, WS) \
            AC(0,0,FS,WS)  AC(1,2,FS,WS)  AC(2,3,FS,WS)  AC(3,4,FS,WS) \
            AC(4,5,FS,WS)  AC(5,6,FS,WS)  AC(6,8,FS,WS) \
            AC(7,13,FS,WS) AC(8,15,FS,WS) AC(9,17,FS,WS) AC(10,19,FS,WS)
        CHANLOOP(LOAD2, CMP3)
        EPIPRE
        const bool ry6 = (y + 2 < HH);        // y+6-4 in [0,160)
        const bool ry7 = (y + 3 < HH);
        EPI(0,37,ry6,0) EPI(1,38,ry6,2) EPI(2,39,ry6,3) EPI(3,40,ry6,4)
        EPI(4,41,ry6,5) EPI(5,42,ry6,6) EPI(6,43,ry6,8)
        EPI(7,44,ry7,1) EPI(8,45,ry7,3) EPI(9,46,ry7,5) EPI(10,47,ry7,7)
    } else {
        // dy8 -> d48..52 dx{0,2,4,6,8}
        const int r0 = RYOFF(8);
        float4 acc[5];
        #pragma unroll
        for (int a = 0; a < 5; ++a) acc[a] = make_float4(0.f,0.f,0.f,0.f);
        float fA[12], fB[12]; float4 wA, wB;
        #define CMP4(FS, WS) \
            AC(0,0,FS,WS) AC(1,2,FS,WS) AC(2,4,FS,WS) AC(3,6,FS,WS) AC(4,8,FS,WS)
        CHANLOOP(LOAD1, CMP4)
        EPIPRE
        const bool ry8 = (y + 4 < HH);
        EPI(0,48,ry8,0) EPI(1,49,ry8,2) EPI(2,50,ry8,4) EPI(3,51,ry8,6) EPI(4,52,ry8,8)
    }
}

extern "C" void kernel_launch(void* const* d_in, const int* in_sizes, int n_in,
                              void* d_out, int out_size, void* d_ws, size_t ws_size,
                              hipStream_t stream) {
    const float* in1 = (const float*)d_in[0];
    const float* in2 = (const float*)d_in[1];
    float* out = (float*)d_out;

    // 5 passes x 1600 blocks of 64 threads = 8000 blocks (8000 waves)
    dim3 grid(8000);
    dim3 block(64);
    cost_volume_5p<<<grid, block, 0, stream>>>(in1, in2, out);
}

// Round 6
// 368.700 us; speedup vs baseline: 1.7450x; 1.0222x over previous
//
#include <hip/hip_runtime.h>

// CostVolume v8 — dy-split INSIDE the workgroup: 9 waves/block, wave w == dy row w.
//
// v7 post-mortem: (a) FETCH 558MB = in1 + ~4.3x in2 — the grid-level pass split
// re-fetched in2 from HBM (passes ran on different CUs at different times; L3
// thrashed by the 295MB streaming set). (b) allocator granted 80 regs vs ~112
// demand -> pipeline squeezed (third failure: design for <=64 regs, don't fight).
// (c) 64-thread blocks hit the ~16 workgroups/CU cap -> only ~2.3 waves/SIMD.
//
// v8 structure: block = 576 threads = 9 waves, all handling the SAME 64
// pixel-quads; wave w accumulates the dx-offsets of window row dy=w.
//  - Per-thread state: max 7 float4 accs + 12-float window + w + addr ~= 55
//    regs -> fits the 64-reg tier naturally (no squeeze, no spill).
//  - in2 quad is read by all 9 waves CONCURRENTLY ON THE SAME CU -> 1 HBM
//    fetch + 8 L1/L2 hits. in1 rows are disjoint across waves -> fetched once.
//    Ideal fetch ~= 210MB (vs 558).
//  - 9-wave blocks escape the workgroup-count cap: 3 blocks/CU = 27 waves/CU.
//  - No barriers, no LDS: co-residency is the only coupling between waves.
//
// out[n,d,y,x] = (1/64) * sum_c in1_pad[n,c, y+dy_d-4, x+dx_d-4] * in2[n,c,y,x]
// One thread owns 4 consecutive x. Window row = 12 floats = 3 aligned float4
// loads shared by 4 pixels and all dx of the row. No guards in the hot loop:
// row index clamped to [0,159], first/last loads clamped into the buffer;
// garbage lands only in acc slots whose TRUE source index is OOB, zeroed in
// the epilogue (OOB-ness of a (d,pixel) is uniform across channels == the
// reference's zero padding). XCD swizzle: 200 contiguous blocks (= one n
// image) per XCD for in1 row reuse in XCD-local L2.

#define HH 160
#define WW 320
#define CHN 64
#define ND 53
#define HW4 (HH * WW * 4)      /* 204800 bytes per (n,c) plane */
#define ROW4 (WW * 4)          /* 1280 bytes per row */
#define IMG4 (CHN * HW4)       /* 13107200 bytes per n image */
#define SIZEB (8 * IMG4)       /* 104857600 bytes total in1 */
#define OIMG4 (ND * HW4)       /* out bytes per n */

__global__ __launch_bounds__(576)
void cost_volume_9w(const float* __restrict__ in1,
                    const float* __restrict__ in2,
                    float* __restrict__ out) {
    const int wv   = threadIdx.x >> 6;        // 0..8 == dy
    const int lane = threadIdx.x & 63;
    const int bid  = blockIdx.x;              // 0..1599
    const int sb   = (bid & 7) * 200 + (bid >> 3);   // XCD swizzle, bijective
    const int q    = sb * 64 + lane;          // pixel-quad id, 0..102399

    const int xg = q % 80;
    const int x0 = xg * 4;
    const int y  = (q / 80) % HH;
    const int n  = q / (80 * HH);

    const char* p1 = (const char*)in1;
    const char* p2 = (const char*)in2;

    // this wave's window row (clamped; OOB handled in epilogue)
    const int yy0 = y + wv - 4;
    const int yc  = yy0 < 0 ? 0 : (yy0 > HH - 1 ? HH - 1 : yy0);
    const int r0  = yc * ROW4;
    const bool ry = (yy0 >= 0) && (yy0 < HH);

    int pc = n * IMG4 + x0 * 4 - 16;          // in1 byte base (c0, row0, x0-4)
    int i2 = n * IMG4 + (y * WW + x0) * 4;    // in2 byte offset (c0)

    const float s = 1.0f / 64.0f;
    char* po = (char*)out + (size_t)n * OIMG4 + (size_t)((y * WW + x0) * 4);
    bool xok[12];
    #pragma unroll
    for (int j = 0; j < 12; ++j) { const int xx = x0 + j - 4; xok[j] = (xx >= 0) && (xx < WW); }

    // acc[A] pixel px += f[J+px] * w[px]   (J = dx)
    #define AC(A, J) \
        acc[A].x = fmaf(f[(J)+0], w.x, acc[A].x); \
        acc[A].y = fmaf(f[(J)+1], w.y, acc[A].y); \
        acc[A].z = fmaf(f[(J)+2], w.z, acc[A].z); \
        acc[A].w = fmaf(f[(J)+3], w.w, acc[A].w);

    // Channel loop: 1 in2 float4 + 3 in1 float4 (ends clamped into buffer).
    // off >= -16 so mid load (off+16) >= 0; max ends exactly at SIZEB.
    #define CHLOOP(ACCS) \
        _Pragma("unroll 1") \
        for (int c = 0; c < CHN; ++c) { \
            const float4 w = *(const float4*)(p2 + i2); \
            float f[12]; \
            { const int off = pc + r0; \
              const int oa = off < 0 ? 0 : off; \
              const int oc = (off + 32 > SIZEB - 16) ? (SIZEB - 16) : (off + 32); \
              const float4 va = *(const float4*)(p1 + oa); \
              const float4 vb = *(const float4*)(p1 + off + 16); \
              const float4 vc = *(const float4*)(p1 + oc); \
              f[0]=va.x; f[1]=va.y; f[2]=va.z;  f[3]=va.w; \
              f[4]=vb.x; f[5]=vb.y; f[6]=vb.z;  f[7]=vb.w; \
              f[8]=vc.x; f[9]=vc.y; f[10]=vc.z; f[11]=vc.w; } \
            ACCS \
            pc += HW4; i2 += HW4; \
        }

    #define EPI(A, D, DX) { \
        float4 rr; \
        rr.x = (ry && xok[(DX)+0]) ? acc[A].x * s : 0.f; \
        rr.y = (ry && xok[(DX)+1]) ? acc[A].y * s : 0.f; \
        rr.z = (ry && xok[(DX)+2]) ? acc[A].z * s : 0.f; \
        rr.w = (ry && xok[(DX)+3]) ? acc[A].w * s : 0.f; \
        *(float4*)(po + (size_t)(D) * HW4) = rr; }

    switch (wv) {
    case 0: { // dy0: dx{0,2,4,6,8} -> d0..4
        float4 acc[5] = {};
        CHLOOP(AC(0,0) AC(1,2) AC(2,4) AC(3,6) AC(4,8))
        EPI(0,0,0) EPI(1,1,2) EPI(2,2,4) EPI(3,3,6) EPI(4,4,8)
        break; }
    case 1: { // dy1: dx{1,3,5,7} -> d5..8
        float4 acc[4] = {};
        CHLOOP(AC(0,1) AC(1,3) AC(2,5) AC(3,7))
        EPI(0,5,1) EPI(1,6,3) EPI(2,7,5) EPI(3,8,7)
        break; }
    case 2: { // dy2: dx{0,2,3,4,5,6,8} -> d9..15
        float4 acc[7] = {};
        CHLOOP(AC(0,0) AC(1,2) AC(2,3) AC(3,4) AC(4,5) AC(5,6) AC(6,8))
        EPI(0,9,0) EPI(1,10,2) EPI(2,11,3) EPI(3,12,4) EPI(4,13,5) EPI(5,14,6) EPI(6,15,8)
        break; }
    case 3: { // dy3: dx{1..7} -> d16..22
        float4 acc[7] = {};
        CHLOOP(AC(0,1) AC(1,2) AC(2,3) AC(3,4) AC(4,5) AC(5,6) AC(6,7))
        EPI(0,16,1) EPI(1,17,2) EPI(2,18,3) EPI(3,19,4) EPI(4,20,5) EPI(5,21,6) EPI(6,22,7)
        break; }
    case 4: { // dy4: dx{0,2,3,4,5,6,8} -> d23..29
        float4 acc[7] = {};
        CHLOOP(AC(0,0) AC(1,2) AC(2,3) AC(3,4) AC(4,5) AC(5,6) AC(6,8))
        EPI(0,23,0) EPI(1,24,2) EPI(2,25,3) EPI(3,26,4) EPI(4,27,5) EPI(5,28,6) EPI(6,29,8)
        break; }
    case 5: { // dy5: dx{1..7} -> d30..36
        float4 acc[7] = {};
        CHLOOP(AC(0,1) AC(1,2) AC(2,3) AC(3,4) AC(4,5) AC(5,6) AC(6,7))
        EPI(0,30,1) EPI(1,31,2) EPI(2,32,3) EPI(3,33,4) EPI(4,34,5) EPI(5,35,6) EPI(6,36,7)
        break; }
    case 6: { // dy6: dx{0,2,3,4,5,6,8} -> d37..43
        float4 acc[7] = {};
        CHLOOP(AC(0,0) AC(1,2) AC(2,3) AC(3,4) AC(4,5) AC(5,6) AC(6,8))
        EPI(0,37,0) EPI(1,38,2) EPI(2,39,3) EPI(3,40,4) EPI(4,41,5) EPI(5,42,6) EPI(6,43,8)
        break; }
    case 7: { // dy7: dx{1,3,5,7} -> d44..47
        float4 acc[4] = {};
        CHLOOP(AC(0,1) AC(1,3) AC(2,5) AC(3,7))
        EPI(0,44,1) EPI(1,45,3) EPI(2,46,5) EPI(3,47,7)
        break; }
    default: { // dy8: dx{0,2,4,6,8} -> d48..52
        float4 acc[5] = {};
        CHLOOP(AC(0,0) AC(1,2) AC(2,4) AC(3,6) AC(4,8))
        EPI(0,48,0) EPI(1,49,2) EPI(2,50,4) EPI(3,51,6) EPI(4,52,8)
        break; }
    }
    #undef AC
    #undef CHLOOP
    #undef EPI
}

extern "C" void kernel_launch(void* const* d_in, const int* in_sizes, int n_in,
                              void* d_out, int out_size, void* d_ws, size_t ws_size,
                              hipStream_t stream) {
    const float* in1 = (const float*)d_in[0];
    const float* in2 = (const float*)d_in[1];
    float* out = (float*)d_out;

    // 1600 blocks x 576 threads (9 waves, one per dy row; 64 pixel-quads/block)
    dim3 grid(1600);
    dim3 block(576);
    cost_volume_9w<<<grid, block, 0, stream>>>(in1, in2, out);
}